// Round 7
// baseline (274.018 us; speedup 1.0000x reference)
//
#include <hip/hip_runtime.h>

#define EPS_ 1e-5f
#define BATCH 32
#define CIN 240
#define H_ 56
#define W_ 56
#define HW 3136          // 56*56
#define C1 24            // init_c
#define R_ 9             // ratio-1
#define C2 216           // C1*R_
#define COUT 240

// ---- workspace layout (floats) ---- total 6464 floats (~26 KB)
#define WS_WT   0        // [240][24]  conv1x1 weights, ci-major, BN1 scale folded
#define WS_B1   5760     // [24]       BN1 bias
#define WS_WDW  5784     // [24][9]    dw weights, BN2 scale folded
#define WS_B2   6000     // [24]       BN2 bias
#define WS_INV3 6024     // [216]
#define WS_T3   6240     // [216]
// t1 (conv1x1+BN1 intermediate) lives in OUT channels [24,48) until the adder
// kernel overwrites them (stream-ordered; every kernel's read set is disjoint
// from its own write set).

__global__ __launch_bounds__(256) void prep_kernel(
    const float* __restrict__ wp,
    const float* __restrict__ g1, const float* __restrict__ b1,
    const float* __restrict__ m1, const float* __restrict__ v1,
    const float* __restrict__ wdw,
    const float* __restrict__ g2, const float* __restrict__ b2,
    const float* __restrict__ m2, const float* __restrict__ v2,
    const float* __restrict__ g3, const float* __restrict__ b3,
    const float* __restrict__ m3, const float* __restrict__ v3,
    float* __restrict__ ws) {
  int i = blockIdx.x * 256 + threadIdx.x;
  if (i < 5760) {
    // transpose w_primary (co-major [24][240]) -> ci-major [240][24], fold BN1
    int ci = i / C1, co = i % C1;
    float s = g1[co] / sqrtf(v1[co] + EPS_);
    ws[WS_WT + ci * C1 + co] = wp[co * CIN + ci] * s;
    if (ci == 0) ws[WS_B1 + co] = b1[co] - m1[co] * s;
  } else if (i < 5760 + C2) {
    int j = i - 5760;           // [0,216): c*9+k
    int c = j / 9;
    float s = g2[c] / sqrtf(v2[c] + EPS_);
    ws[WS_WDW + j] = wdw[j] * s;
    if (j % 9 == 0) ws[WS_B2 + c] = b2[c] - m2[c] * s;
  } else if (i < 5976 + C2) {
    int j = i - 5976;           // [0,216)
    float s = g3[j] / sqrtf(v3[j] + EPS_);
    ws[WS_INV3 + j] = s;
    ws[WS_T3 + j] = b3[j] - m3[j] * s;
  }
}

// 1x1 conv (240 -> 24) + BN1 -> out channels [24,48).
// Block = 256 threads = 4 waves over the SAME 64 pixels; lane = 1 pixel.
// Wave kq reduces ci in [60kq, 60kq+60); acc[24]/thread (~50 VGPR, no spills;
// 1568 blocks x 4 waves = 6272 waves = 6 waves/SIMD TLP).
// Weights are read with WAVE-UNIFORM float4 addresses straight from global ->
// scalar s_load_dwordx4 path (or uniform L1-broadcast VMEM): zero LDS cost.
// (R6 used ds_read_b128 broadcasts: 2.26M b128 insts = ~44us of LDS pipe.)
// LDS holds only the 24.6 KB cross-wave reduction buffer.
__global__ __launch_bounds__(256) void conv1x1_kernel(
    const float* __restrict__ x, const float* __restrict__ wt,
    const float* __restrict__ bias1, float* __restrict__ out) {
  __shared__ float red[6144];    // [4][24][64]
  const int tid  = threadIdx.x;
  const int lane = tid & 63;
  const int kq   = tid >> 6;     // K-chunk 0..3

  const int P   = blockIdx.x * 64 + lane;   // global pixel; 49 blocks/batch
  const int b   = P / HW;
  const int hw  = P - b * HW;
  const int ci0 = kq * 60;
  const float* xp    = x + ((size_t)b * CIN + ci0) * HW + hw;
  const float* wbase = wt + ci0 * C1;       // wave-uniform

  float acc[C1];
#pragma unroll
  for (int i = 0; i < C1; ++i) acc[i] = 0.f;

  float A[6], B[6];
#pragma unroll
  for (int j = 0; j < 6; ++j) A[j] = xp[(size_t)j * HW];
#pragma unroll
  for (int j = 0; j < 6; ++j) B[j] = xp[(size_t)(6 + j) * HW];

  auto consume = [&](const float* buf, int cb) {
#pragma unroll
    for (int j = 0; j < 6; ++j) {
      const float xv = buf[j];
      const float* wr = wbase + (cb + j) * C1;   // uniform address
#pragma unroll
      for (int k = 0; k < 6; ++k) {
        const float4 wq = *(const float4*)(wr + 4 * k);  // s_load_dwordx4
        acc[4*k+0] = fmaf(wq.x, xv, acc[4*k+0]);
        acc[4*k+1] = fmaf(wq.y, xv, acc[4*k+1]);
        acc[4*k+2] = fmaf(wq.z, xv, acc[4*k+2]);
        acc[4*k+3] = fmaf(wq.w, xv, acc[4*k+3]);
      }
    }
  };

#pragma unroll 1
  for (int g = 0; g < 4; ++g) {
    const int c = 12 * g;
    consume(A, c);
#pragma unroll
    for (int j = 0; j < 6; ++j) A[j] = xp[(size_t)(c + 12 + j) * HW];
    consume(B, c + 6);
#pragma unroll
    for (int j = 0; j < 6; ++j) B[j] = xp[(size_t)(c + 18 + j) * HW];
  }
  consume(A, 48);
  consume(B, 54);

#pragma unroll
  for (int i = 0; i < C1; ++i) red[(kq * C1 + i) * 64 + lane] = acc[i];
  __syncthreads();

  // wave kq finishes channels [6kq, 6kq+6)
  float* o = out + ((size_t)b * COUT + C1) * HW + hw;
#pragma unroll
  for (int i = 0; i < 6; ++i) {
    const int co = kq * 6 + i;
    float v = red[(0 * C1 + co) * 64 + lane]
            + red[(1 * C1 + co) * 64 + lane]
            + red[(2 * C1 + co) * 64 + lane]
            + red[(3 * C1 + co) * 64 + lane]
            + bias1[co];
    o[(size_t)co * HW] = v;
  }
}

// depthwise 3x3 conv + BN2: reads t1 from out ch [24,48), writes x1 to ch [0,24).
// Thread = 4-pixel quad; zero-substitution at borders is exact (w * 0 == 0).
__global__ __launch_bounds__(256) void dw_kernel(
    const float* __restrict__ outr, const float* __restrict__ wdwf,
    const float* __restrict__ bias2, float* __restrict__ out) {
  const int c = blockIdx.y, b = blockIdx.z;
  const int q = blockIdx.x * 256 + threadIdx.x;   // quad id in [0,784)
  if (q >= 784) return;
  const int h  = q / 14;
  const int w0 = (q - h * 14) * 4;
  const float* in = outr + ((size_t)b * COUT + C1 + c) * HW;

  float wk[9];
#pragma unroll
  for (int k = 0; k < 9; ++k) wk[k] = wdwf[c * 9 + k];   // uniform -> scalar
  const float bb = bias2[c];

  float xr[3][6];
#pragma unroll
  for (int kh = 0; kh < 3; ++kh) {
    const int hh = h + kh - 1;
    const bool rok = (hh >= 0) & (hh < H_);
    const float* rp = in + hh * W_;
    xr[kh][0] = (rok && w0 > 0) ? rp[w0 - 1] : 0.f;
    if (rok) {
      const float4 m = *(const float4*)(rp + w0);
      xr[kh][1] = m.x; xr[kh][2] = m.y; xr[kh][3] = m.z; xr[kh][4] = m.w;
    } else {
      xr[kh][1] = 0.f; xr[kh][2] = 0.f; xr[kh][3] = 0.f; xr[kh][4] = 0.f;
    }
    xr[kh][5] = (rok && w0 < W_ - 4) ? rp[w0 + 4] : 0.f;
  }

  float4 v = {bb, bb, bb, bb};
#pragma unroll
  for (int kh = 0; kh < 3; ++kh) {
#pragma unroll
    for (int kw = 0; kw < 3; ++kw) {
      const float t = wk[kh * 3 + kw];
      v.x = fmaf(xr[kh][kw + 0], t, v.x);
      v.y = fmaf(xr[kh][kw + 1], t, v.y);
      v.z = fmaf(xr[kh][kw + 2], t, v.z);
      v.w = fmaf(xr[kh][kw + 3], t, v.w);
    }
  }
  *(float4*)(out + ((size_t)b * COUT + c) * HW + h * W_ + w0) = v;
}

// adder depthwise (24 -> 216) + BN3 + ReLU: reads x1 from out ch [0,24),
// writes x2 to out ch [24,240). Thread = 4-pixel quad, all 9 r-channels.
// Reference pads x1 with zeros and still takes |0 - tap| at borders, so OOB
// positions contribute fabsf(tap) -- we substitute 0, never skip taps.
__global__ __launch_bounds__(256) void adder_kernel(
    const float* __restrict__ outr, const float* __restrict__ wadd,
    const float* __restrict__ inv3, const float* __restrict__ t3,
    float* __restrict__ out) {
  const int c = blockIdx.y, b = blockIdx.z;
  __shared__ float taps[R_][3][4];   // [r][kh][kw, padded to 4]
  __shared__ float s3[R_], t3s[R_];
  const int tid = threadIdx.x;
  if (tid < 108) {
    int r = tid / 12, kh = (tid / 4) % 3, kw = tid & 3;
    taps[r][kh][kw] = (kw < 3) ? wadd[((c * R_ + r) * 3 + kh) * 3 + kw] : 0.f;
  } else if (tid >= 128 && tid < 128 + R_) {
    int r = tid - 128;
    s3[r]  = inv3[c * R_ + r];
    t3s[r] = t3[c * R_ + r];
  }
  __syncthreads();

  const int q = blockIdx.x * 256 + tid;   // pixel quad id in [0,784)
  if (q >= 784) return;
  const int h  = q / 14;
  const int w0 = (q - h * 14) * 4;
  const float* in = outr + ((size_t)b * COUT + c) * HW;

  float xr[3][6];
#pragma unroll
  for (int kh = 0; kh < 3; ++kh) {
    const int hh = h + kh - 1;
    const bool rok = (hh >= 0) & (hh < H_);
    const float* rp = in + hh * W_;
    xr[kh][0] = (rok && w0 > 0) ? rp[w0 - 1] : 0.f;
    if (rok) {
      const float4 m = *(const float4*)(rp + w0);
      xr[kh][1] = m.x; xr[kh][2] = m.y; xr[kh][3] = m.z; xr[kh][4] = m.w;
    } else {
      xr[kh][1] = 0.f; xr[kh][2] = 0.f; xr[kh][3] = 0.f; xr[kh][4] = 0.f;
    }
    xr[kh][5] = (rok && w0 < W_ - 4) ? rp[w0 + 4] : 0.f;
  }

#pragma unroll
  for (int r = 0; r < R_; ++r) {
    float a0 = 0.f, a1 = 0.f, a2 = 0.f, a3 = 0.f;
#pragma unroll
    for (int kh = 0; kh < 3; ++kh) {
#pragma unroll
      for (int kw = 0; kw < 3; ++kw) {
        const float t = taps[r][kh][kw];
        a0 += fabsf(xr[kh][kw + 0] - t);
        a1 += fabsf(xr[kh][kw + 1] - t);
        a2 += fabsf(xr[kh][kw + 2] - t);
        a3 += fabsf(xr[kh][kw + 3] - t);
      }
    }
    const float s = s3[r], bb = t3s[r];
    float4 v;
    v.x = fmaxf(fmaf(-s, a0, bb), 0.f);
    v.y = fmaxf(fmaf(-s, a1, bb), 0.f);
    v.z = fmaxf(fmaf(-s, a2, bb), 0.f);
    v.w = fmaxf(fmaf(-s, a3, bb), 0.f);
    *(float4*)(out + ((size_t)b * COUT + C1 + c * R_ + r) * HW + h * W_ + w0) = v;
  }
}

extern "C" void kernel_launch(void* const* d_in, const int* in_sizes, int n_in,
                              void* d_out, int out_size, void* d_ws, size_t ws_size,
                              hipStream_t stream) {
  const float* x    = (const float*)d_in[0];
  const float* wp   = (const float*)d_in[1];
  const float* g1   = (const float*)d_in[2];
  const float* b1   = (const float*)d_in[3];
  const float* m1   = (const float*)d_in[4];
  const float* v1   = (const float*)d_in[5];
  const float* wdw  = (const float*)d_in[6];
  const float* g2   = (const float*)d_in[7];
  const float* b2   = (const float*)d_in[8];
  const float* m2   = (const float*)d_in[9];
  const float* v2   = (const float*)d_in[10];
  const float* wadd = (const float*)d_in[11];
  const float* g3   = (const float*)d_in[12];
  const float* b3   = (const float*)d_in[13];
  const float* m3   = (const float*)d_in[14];
  const float* v3   = (const float*)d_in[15];

  float* ws  = (float*)d_ws;
  float* out = (float*)d_out;

  // fold BN params / transpose weights (~26 KB of ws)
  prep_kernel<<<25, 256, 0, stream>>>(wp, g1, b1, m1, v1, wdw, g2, b2, m2, v2,
                                      g3, b3, m3, v3, ws);

  // 1x1 conv + BN1 -> t1 in out channels [24,48). 1568 blocks x 64 px x 4 waves.
  conv1x1_kernel<<<1568, 256, 0, stream>>>(x, ws + WS_WT, ws + WS_B1, out);

  // dw 3x3 + BN2: t1 (ch 24..47) -> x1 (ch 0..23)
  dw_kernel<<<dim3(4, C1, BATCH), 256, 0, stream>>>(out, ws + WS_WDW,
                                                    ws + WS_B2, out);

  // adder + BN3 + ReLU: x1 (ch 0..23) -> x2 (ch 24..239)
  adder_kernel<<<dim3(4, C1, BATCH), 256, 0, stream>>>(out, wadd, ws + WS_INV3,
                                                       ws + WS_T3, out);
}

// Round 8
// 218.772 us; speedup vs baseline: 1.2525x; 1.2525x over previous
//
#include <hip/hip_runtime.h>

#define EPS_ 1e-5f
#define BATCH 32
#define CIN 240
#define H_ 56
#define W_ 56
#define HW 3136          // 56*56
#define C1 24            // init_c
#define R_ 9             // ratio-1
#define C2 216           // C1*R_
#define COUT 240

// ---- workspace layout (floats) ----
#define WS_B1   5760     // [24]       BN1 bias
#define WS_WDW  5784     // [24][9]    dw weights, BN2 scale folded
#define WS_B2   6000     // [24]       BN2 bias
#define WS_INV3 6024     // [216]
#define WS_T3   6240     // [216]
#define WS_WF   6464     // [8192] f16 = 16 KB: conv1x1 weights in MFMA A-frag
                         // layout [step s<8][co-tile t<2][lane<64][j<8],
                         // value = w[co = t*16+(lane&15)][ci = s*32+(lane>>4)*8+j]
                         // * bn1_scale[co]; zero-padded for ci>=240 / co>=24.
// t1 (conv1x1+BN1 intermediate) lives in OUT channels [24,48) until the adder
// kernel overwrites them (stream-ordered; read sets disjoint from write sets).

typedef __attribute__((ext_vector_type(8))) _Float16 v8h;
typedef __attribute__((ext_vector_type(4))) float f32x4;

__global__ __launch_bounds__(256) void prep_kernel(
    const float* __restrict__ wp,
    const float* __restrict__ g1, const float* __restrict__ b1,
    const float* __restrict__ m1, const float* __restrict__ v1,
    const float* __restrict__ wdw,
    const float* __restrict__ g2, const float* __restrict__ b2,
    const float* __restrict__ m2, const float* __restrict__ v2,
    const float* __restrict__ g3, const float* __restrict__ b3,
    const float* __restrict__ m3, const float* __restrict__ v3,
    float* __restrict__ ws) {
  int i = blockIdx.x * 256 + threadIdx.x;
  if (i < C1) {
    float s = g1[i] / sqrtf(v1[i] + EPS_);
    ws[WS_B1 + i] = b1[i] - m1[i] * s;
  } else if (i >= 240 && i < 240 + C2) {
    int j = i - 240;            // [0,216): c*9+k
    int c = j / 9;
    float s = g2[c] / sqrtf(v2[c] + EPS_);
    ws[WS_WDW + j] = wdw[j] * s;
    if (j % 9 == 0) ws[WS_B2 + c] = b2[c] - m2[c] * s;
  } else if (i >= 456 && i < 456 + C2) {
    int j = i - 456;            // [0,216)
    float s = g3[j] / sqrtf(v3[j] + EPS_);
    ws[WS_INV3 + j] = s;
    ws[WS_T3 + j] = b3[j] - m3[j] * s;
  } else if (i >= 1024 && i < 9216) {
    int k  = i - 1024;          // [0,8192): ((s*2+t)*64 + l)*8 + j
    int j  = k & 7;
    int l  = (k >> 3) & 63;
    int t  = (k >> 9) & 1;
    int s  = k >> 10;
    int co = t * 16 + (l & 15);
    int ci = s * 32 + ((l >> 4) * 8) + j;
    _Float16 v = (_Float16)0.f;
    if (co < C1 && ci < CIN) {
      float sc = g1[co] / sqrtf(v1[co] + EPS_);
      v = (_Float16)(wp[co * CIN + ci] * sc);
    }
    ((_Float16*)(ws + WS_WF))[k] = v;
  }
}

// 1x1 conv (240 -> 24) + BN1 -> out channels [24,48), via MFMA f16.
// Wave = one 16-px tile. A = weights (pre-swizzled wfrag, one dwordx4/lane,
// L1-hot), B = x (8 dword loads/step, cvt f32->f16), acc fp32 in AGPR.
// K = 240 padded to 8 steps of 32 (weights zero-padded; x guarded last step).
// co = 24 via two 16-co tiles (tile1 rows 8..15 masked at store).
// D layout (HW-verified): col = lane&15 = px, row = (lane>>4)*4 + reg = co.
__global__ __launch_bounds__(256) void conv1x1_kernel(
    const float* __restrict__ x, const _Float16* __restrict__ wf,
    const float* __restrict__ bias1, float* __restrict__ out) {
  const int tid  = threadIdx.x;
  const int lane = tid & 63;
  const int q    = lane >> 4;            // quad 0..3
  const int n    = lane & 15;            // px within tile
  const int tile = blockIdx.x * 4 + (tid >> 6);   // [0, 6272)
  const int pxb  = tile * 16;            // 196 tiles per image; never crosses b
  const int b    = pxb / HW;
  const int hw0  = pxb - b * HW;
  const float* xb = x + (size_t)b * CIN * HW + hw0 + n;
  const v8h* wfl  = (const v8h*)wf;

  f32x4 acc0 = {0.f, 0.f, 0.f, 0.f};
  f32x4 acc1 = {0.f, 0.f, 0.f, 0.f};
  const int cb = q * 8;                  // this quad's k-offset within a step

  float xv[8], xw[8];
#pragma unroll
  for (int j = 0; j < 8; ++j) xv[j] = xb[(size_t)(cb + j) * HW];  // step 0

#pragma unroll
  for (int s = 0; s < 8; ++s) {
    if (s < 7) {                         // prefetch next step's x
      const int ci0 = (s + 1) * 32 + cb;
      if (s + 1 == 7) {
#pragma unroll
        for (int j = 0; j < 8; ++j)
          xw[j] = (q < 2) ? xb[(size_t)(ci0 + j) * HW] : 0.f;  // ci>=240 -> 0
      } else {
#pragma unroll
        for (int j = 0; j < 8; ++j) xw[j] = xb[(size_t)(ci0 + j) * HW];
      }
    }
    v8h bf;
#pragma unroll
    for (int j = 0; j < 8; ++j) bf[j] = (_Float16)xv[j];
    const v8h a0 = wfl[(s * 2 + 0) * 64 + lane];
    const v8h a1 = wfl[(s * 2 + 1) * 64 + lane];
    acc0 = __builtin_amdgcn_mfma_f32_16x16x32_f16(a0, bf, acc0, 0, 0, 0);
    acc1 = __builtin_amdgcn_mfma_f32_16x16x32_f16(a1, bf, acc1, 0, 0, 0);
    if (s < 7) {
#pragma unroll
      for (int j = 0; j < 8; ++j) xv[j] = xw[j];
    }
  }

  float* o = out + ((size_t)b * COUT + C1) * HW + hw0 + n;
#pragma unroll
  for (int r = 0; r < 4; ++r) {
    const int co = q * 4 + r;            // 0..15
    o[(size_t)co * HW] = acc0[r] + bias1[co];
  }
  if (q < 2) {
#pragma unroll
    for (int r = 0; r < 4; ++r) {
      const int co = 16 + q * 4 + r;     // 16..23
      o[(size_t)co * HW] = acc1[r] + bias1[co];
    }
  }
}

// depthwise 3x3 conv + BN2: reads t1 from out ch [24,48), writes x1 to ch [0,24).
// Thread = 4-pixel quad; zero-substitution at borders is exact (w * 0 == 0).
__global__ __launch_bounds__(256) void dw_kernel(
    const float* __restrict__ outr, const float* __restrict__ wdwf,
    const float* __restrict__ bias2, float* __restrict__ out) {
  const int c = blockIdx.y, b = blockIdx.z;
  const int q = blockIdx.x * 256 + threadIdx.x;   // quad id in [0,784)
  if (q >= 784) return;
  const int h  = q / 14;
  const int w0 = (q - h * 14) * 4;
  const float* in = outr + ((size_t)b * COUT + C1 + c) * HW;

  float wk[9];
#pragma unroll
  for (int k = 0; k < 9; ++k) wk[k] = wdwf[c * 9 + k];   // uniform -> scalar
  const float bb = bias2[c];

  float xr[3][6];
#pragma unroll
  for (int kh = 0; kh < 3; ++kh) {
    const int hh = h + kh - 1;
    const bool rok = (hh >= 0) & (hh < H_);
    const float* rp = in + hh * W_;
    xr[kh][0] = (rok && w0 > 0) ? rp[w0 - 1] : 0.f;
    if (rok) {
      const float4 m = *(const float4*)(rp + w0);
      xr[kh][1] = m.x; xr[kh][2] = m.y; xr[kh][3] = m.z; xr[kh][4] = m.w;
    } else {
      xr[kh][1] = 0.f; xr[kh][2] = 0.f; xr[kh][3] = 0.f; xr[kh][4] = 0.f;
    }
    xr[kh][5] = (rok && w0 < W_ - 4) ? rp[w0 + 4] : 0.f;
  }

  float4 v = {bb, bb, bb, bb};
#pragma unroll
  for (int kh = 0; kh < 3; ++kh) {
#pragma unroll
    for (int kw = 0; kw < 3; ++kw) {
      const float t = wk[kh * 3 + kw];
      v.x = fmaf(xr[kh][kw + 0], t, v.x);
      v.y = fmaf(xr[kh][kw + 1], t, v.y);
      v.z = fmaf(xr[kh][kw + 2], t, v.z);
      v.w = fmaf(xr[kh][kw + 3], t, v.w);
    }
  }
  *(float4*)(out + ((size_t)b * COUT + c) * HW + h * W_ + w0) = v;
}

// adder depthwise (24 -> 216) + BN3 + ReLU: reads x1 from out ch [0,24),
// writes x2 to out ch [24,240). Thread = 4-pixel quad, all 9 r-channels.
// Reference pads x1 with zeros and still takes |0 - tap| at borders, so OOB
// positions contribute fabsf(tap) -- we substitute 0, never skip taps.
__global__ __launch_bounds__(256) void adder_kernel(
    const float* __restrict__ outr, const float* __restrict__ wadd,
    const float* __restrict__ inv3, const float* __restrict__ t3,
    float* __restrict__ out) {
  const int c = blockIdx.y, b = blockIdx.z;
  __shared__ float taps[R_][3][4];   // [r][kh][kw, padded to 4]
  __shared__ float s3[R_], t3s[R_];
  const int tid = threadIdx.x;
  if (tid < 108) {
    int r = tid / 12, kh = (tid / 4) % 3, kw = tid & 3;
    taps[r][kh][kw] = (kw < 3) ? wadd[((c * R_ + r) * 3 + kh) * 3 + kw] : 0.f;
  } else if (tid >= 128 && tid < 128 + R_) {
    int r = tid - 128;
    s3[r]  = inv3[c * R_ + r];
    t3s[r] = t3[c * R_ + r];
  }
  __syncthreads();

  const int q = blockIdx.x * 256 + tid;   // pixel quad id in [0,784)
  if (q >= 784) return;
  const int h  = q / 14;
  const int w0 = (q - h * 14) * 4;
  const float* in = outr + ((size_t)b * COUT + c) * HW;

  float xr[3][6];
#pragma unroll
  for (int kh = 0; kh < 3; ++kh) {
    const int hh = h + kh - 1;
    const bool rok = (hh >= 0) & (hh < H_);
    const float* rp = in + hh * W_;
    xr[kh][0] = (rok && w0 > 0) ? rp[w0 - 1] : 0.f;
    if (rok) {
      const float4 m = *(const float4*)(rp + w0);
      xr[kh][1] = m.x; xr[kh][2] = m.y; xr[kh][3] = m.z; xr[kh][4] = m.w;
    } else {
      xr[kh][1] = 0.f; xr[kh][2] = 0.f; xr[kh][3] = 0.f; xr[kh][4] = 0.f;
    }
    xr[kh][5] = (rok && w0 < W_ - 4) ? rp[w0 + 4] : 0.f;
  }

#pragma unroll
  for (int r = 0; r < R_; ++r) {
    float a0 = 0.f, a1 = 0.f, a2 = 0.f, a3 = 0.f;
#pragma unroll
    for (int kh = 0; kh < 3; ++kh) {
#pragma unroll
      for (int kw = 0; kw < 3; ++kw) {
        const float t = taps[r][kh][kw];
        a0 += fabsf(xr[kh][kw + 0] - t);
        a1 += fabsf(xr[kh][kw + 1] - t);
        a2 += fabsf(xr[kh][kw + 2] - t);
        a3 += fabsf(xr[kh][kw + 3] - t);
      }
    }
    const float s = s3[r], bb = t3s[r];
    float4 v;
    v.x = fmaxf(fmaf(-s, a0, bb), 0.f);
    v.y = fmaxf(fmaf(-s, a1, bb), 0.f);
    v.z = fmaxf(fmaf(-s, a2, bb), 0.f);
    v.w = fmaxf(fmaf(-s, a3, bb), 0.f);
    *(float4*)(out + ((size_t)b * COUT + C1 + c * R_ + r) * HW + h * W_ + w0) = v;
  }
}

extern "C" void kernel_launch(void* const* d_in, const int* in_sizes, int n_in,
                              void* d_out, int out_size, void* d_ws, size_t ws_size,
                              hipStream_t stream) {
  const float* x    = (const float*)d_in[0];
  const float* wp   = (const float*)d_in[1];
  const float* g1   = (const float*)d_in[2];
  const float* b1   = (const float*)d_in[3];
  const float* m1   = (const float*)d_in[4];
  const float* v1   = (const float*)d_in[5];
  const float* wdw  = (const float*)d_in[6];
  const float* g2   = (const float*)d_in[7];
  const float* b2   = (const float*)d_in[8];
  const float* m2   = (const float*)d_in[9];
  const float* v2   = (const float*)d_in[10];
  const float* wadd = (const float*)d_in[11];
  const float* g3   = (const float*)d_in[12];
  const float* b3   = (const float*)d_in[13];
  const float* m3   = (const float*)d_in[14];
  const float* v3   = (const float*)d_in[15];

  float* ws  = (float*)d_ws;
  float* out = (float*)d_out;

  // fold BN params + build f16 MFMA weight fragments (~42 KB of ws)
  prep_kernel<<<36, 256, 0, stream>>>(wp, g1, b1, m1, v1, wdw, g2, b2, m2, v2,
                                      g3, b3, m3, v3, ws);

  // 1x1 conv + BN1 (MFMA f16) -> t1 in out ch [24,48). 1568 blocks x 4 tiles.
  conv1x1_kernel<<<1568, 256, 0, stream>>>(x, (const _Float16*)(ws + WS_WF),
                                           ws + WS_B1, out);

  // dw 3x3 + BN2: t1 (ch 24..47) -> x1 (ch 0..23)
  dw_kernel<<<dim3(4, C1, BATCH), 256, 0, stream>>>(out, ws + WS_WDW,
                                                    ws + WS_B2, out);

  // adder + BN3 + ReLU: x1 (ch 0..23) -> x2 (ch 24..239)
  adder_kernel<<<dim3(4, C1, BATCH), 256, 0, stream>>>(out, wadd, ws + WS_INV3,
                                                       ws + WS_T3, out);
}